// Round 9
// baseline (241.251 us; speedup 1.0000x reference)
//
#include <hip/hip_runtime.h>

// ABLATION ROUND (R9). Five kernels so far all ~59-67us with every pipe <35%.
// Fork to resolve: (a) R/W-mix memory ceiling ~2.5 TB/s  vs  (b) dependent-chain
// latency of the compute between load and store (shfl latency invisible in counters).
// Launch: copy x3 passes, affine x3 passes, full KAN last (validates d_out).
// Per-pass time = dur/3 for the x3 kernels.

#define NCH     192
#define TPB     256
#define UNROLL  4
#define BLOCKS  6144                 // 6144 * 256 * 4 = 6,291,456 f32x4 exactly

typedef float f32x4 __attribute__((ext_vector_type(4)));

// ---------- variant 1: pure copy, 3 passes ----------
__global__ __launch_bounds__(TPB) void kan_copy3_kernel(
    const float* __restrict__ x, float* __restrict__ out)
{
    const int base = blockIdx.x * (TPB * UNROLL) + threadIdx.x;
    const f32x4* __restrict__ x4 = reinterpret_cast<const f32x4*>(x);
    f32x4* __restrict__ o4 = reinterpret_cast<f32x4*>(out);
    #pragma unroll 1
    for (int p = 0; p < 3; ++p) {
        f32x4 v0 = x4[base + 0 * TPB];
        f32x4 v1 = x4[base + 1 * TPB];
        f32x4 v2 = x4[base + 2 * TPB];
        f32x4 v3 = x4[base + 3 * TPB];
        o4[base + 0 * TPB] = v0;
        o4[base + 1 * TPB] = v1;
        o4[base + 2 * TPB] = v2;
        o4[base + 3 * TPB] = v3;
        __builtin_amdgcn_s_waitcnt(0);          // serialize passes
        __builtin_amdgcn_sched_barrier(0);
    }
}

// ---------- variant 2: affine only (1 fma/elem), 3 passes ----------
__global__ __launch_bounds__(TPB) void kan_affine3_kernel(
    const float* __restrict__ x, const float* __restrict__ id_gain,
    const float* __restrict__ bias, float* __restrict__ out)
{
    const int base = blockIdx.x * (TPB * UNROLL) + threadIdx.x;
    const int c = blockIdx.x % NCH;
    float g_c = id_gain[c], s_c = bias[c];
    const f32x4* __restrict__ x4 = reinterpret_cast<const f32x4*>(x);
    f32x4* __restrict__ o4 = reinterpret_cast<f32x4*>(out);
    #pragma unroll 1
    for (int p = 0; p < 3; ++p) {
        #pragma unroll
        for (int k = 0; k < UNROLL; ++k) {
            f32x4 v = x4[base + k * TPB];
            f32x4 ov;
            ov.x = fmaf(g_c, v.x, s_c);
            ov.y = fmaf(g_c, v.y, s_c);
            ov.z = fmaf(g_c, v.z, s_c);
            ov.w = fmaf(g_c, v.w, s_c);
            o4[base + k * TPB] = ov;
        }
        __builtin_amdgcn_s_waitcnt(0);          // serialize passes
        __builtin_amdgcn_sched_barrier(0);
    }
}

// ---------- variant 3: full KAN (R8, passes at absmax 0.0625) ----------
__device__ __forceinline__ unsigned bf16_rtn(float f) {
    unsigned u = __builtin_bit_cast(unsigned, f);
    return (u + 0x7FFFu + ((u >> 16) & 1u)) >> 16;   // round-to-nearest-even bf16
}
__device__ __forceinline__ float lo_bf16(unsigned p) {
    unsigned v = p << 16;  return __builtin_bit_cast(float, v);
}
__device__ __forceinline__ float hi_bf16(unsigned p) {
    unsigned v = p & 0xFFFF0000u;  return __builtin_bit_cast(float, v);
}

__device__ __forceinline__ float kan_elem(float xx, float a_c, float b_c,
                                          float g_c, float s_c, unsigned pk) {
    float xa = fmaf(xx, a_c, b_c);
    xa = fminf(fmaxf(xa, -1.5f), 1.5f);
    float u  = fmaf(xa, 15.5f, 15.5f);
    float fi = floorf(u);
    float t  = u - fi;
    int   i  = (int)fi;
    int   ic = min(max(i, -2), 33);
    unsigned plo = __shfl(pk, ic + 2, 64);
    unsigned phi = __shfl(pk, ic + 4, 64);
    float a0 = lo_bf16(plo), a1 = hi_bf16(plo);
    float a2 = lo_bf16(phi), a3 = hi_bf16(phi);
    float s  = 1.0f - t;
    float t2 = t * t, s2 = s * s;
    const float k6 = 1.0f / 6.0f;
    float w0 = s2 * s * k6;
    float w3 = t2 * t * k6;
    float w1 = fmaf(t2, fmaf(t, 0.5f, -1.0f), 2.0f / 3.0f);
    float w2 = fmaf(s2, fmaf(s, 0.5f, -1.0f), 2.0f / 3.0f);
    float spline = fmaf(a0, w0, fmaf(a1, w1, fmaf(a2, w2, a3 * w3)));
    return fmaf(g_c, xx, spline + s_c);
}

__device__ __forceinline__ f32x4 kan4(f32x4 xv, float a_c, float b_c,
                                      float g_c, float s_c, unsigned pk) {
    f32x4 ov;
    ov.x = kan_elem(xv.x, a_c, b_c, g_c, s_c, pk);
    ov.y = kan_elem(xv.y, a_c, b_c, g_c, s_c, pk);
    ov.z = kan_elem(xv.z, a_c, b_c, g_c, s_c, pk);
    ov.w = kan_elem(xv.w, a_c, b_c, g_c, s_c, pk);
    return ov;
}

__global__ __launch_bounds__(TPB) void kan_cubic_kernel(
    const float* __restrict__ x, const float* __restrict__ a,
    const float* __restrict__ b, const float* __restrict__ alpha,
    const float* __restrict__ id_gain, const float* __restrict__ bias,
    float* __restrict__ out)
{
    const int tid  = threadIdx.x;
    const int lane = tid & 63;
    const int blk  = blockIdx.x;
    const int base = blk * (TPB * UNROLL) + tid;

    const int c = blk % NCH;
    float a_c = a[c];
    float b_c = b[c];
    float g_c = id_gain[c];
    float s_c = bias[c];
    int kl = min(max(lane - 3, 0), 31);
    int kh = min(max(lane - 2, 0), 31);
    float alo = alpha[(c << 5) + kl];
    float ahi = alpha[(c << 5) + kh];
    unsigned pk = (bf16_rtn(ahi) << 16) | bf16_rtn(alo);

    const f32x4* __restrict__ x4 = reinterpret_cast<const f32x4*>(x);
    f32x4* __restrict__ o4 = reinterpret_cast<f32x4*>(out);

    f32x4 v0 = x4[base + 0 * TPB];
    f32x4 v1 = x4[base + 1 * TPB];
    f32x4 v2 = x4[base + 2 * TPB];
    f32x4 v3 = x4[base + 3 * TPB];
    __builtin_amdgcn_sched_barrier(0);

    o4[base + 0 * TPB] = kan4(v0, a_c, b_c, g_c, s_c, pk);
    o4[base + 1 * TPB] = kan4(v1, a_c, b_c, g_c, s_c, pk);
    o4[base + 2 * TPB] = kan4(v2, a_c, b_c, g_c, s_c, pk);
    o4[base + 3 * TPB] = kan4(v3, a_c, b_c, g_c, s_c, pk);
}

extern "C" void kernel_launch(void* const* d_in, const int* in_sizes, int n_in,
                              void* d_out, int out_size, void* d_ws, size_t ws_size,
                              hipStream_t stream) {
    const float* x       = (const float*)d_in[0];
    const float* a       = (const float*)d_in[1];
    const float* b       = (const float*)d_in[2];
    const float* alpha   = (const float*)d_in[3];
    const float* id_gain = (const float*)d_in[4];
    const float* bias    = (const float*)d_in[5];
    float* out = (float*)d_out;
    // Ablation: copy x3, affine x3, then the real kernel LAST (validates d_out).
    kan_copy3_kernel<<<BLOCKS, TPB, 0, stream>>>(x, out);
    kan_affine3_kernel<<<BLOCKS, TPB, 0, stream>>>(x, id_gain, bias, out);
    kan_cubic_kernel<<<BLOCKS, TPB, 0, stream>>>(x, a, b, alpha, id_gain, bias, out);
}

// Round 10
// 210.673 us; speedup vs baseline: 1.1451x; 1.1451x over previous
//
#include <hip/hip_runtime.h>

// R10: combined fix + ablation.
// Facts so far: copy/affine pass ~9.6us; full KAN 59us; halving DS ops: no change;
// all rounds compiled at VGPR<=32 (single-arg launch_bounds -> max-occupancy target
// -> serialized schedule, zero cross-element ILP). R10 unlocks VGPRs
// (__launch_bounds__(256,1)) and ablates shfl-vs-VALU inside the same launch:
//   1) kan_spline_ns_kernel x3 passes (spline math, NO shfl - arithmetic junk taps)
//   2) kan_cubic_kernel (real, last, validates d_out)
// Decode via dur_us: ~170 both fixed / ~210 shfl is wall / ~340 VALU chain is wall.

#define NCH     192
#define TPB     256
#define UNROLL  4
#define BLOCKS  6144                 // 6144 * 256 * 4 = 6,291,456 f32x4 exactly

typedef float f32x4 __attribute__((ext_vector_type(4)));

__device__ __forceinline__ unsigned bf16_rtn(float f) {
    unsigned u = __builtin_bit_cast(unsigned, f);
    return (u + 0x7FFFu + ((u >> 16) & 1u)) >> 16;   // round-to-nearest-even bf16
}
__device__ __forceinline__ float lo_bf16(unsigned p) {
    unsigned v = p << 16;  return __builtin_bit_cast(float, v);
}
__device__ __forceinline__ float hi_bf16(unsigned p) {
    unsigned v = p & 0xFFFF0000u;  return __builtin_bit_cast(float, v);
}

// ---- shared spline tail: unpack two bf16 pairs + weight tree ----
__device__ __forceinline__ float spline_tail(float xx, float t, float g_c, float s_c,
                                             unsigned plo, unsigned phi) {
    float a0 = lo_bf16(plo), a1 = hi_bf16(plo);
    float a2 = lo_bf16(phi), a3 = hi_bf16(phi);
    float s  = 1.0f - t;
    float t2 = t * t, s2 = s * s;
    const float k6 = 1.0f / 6.0f;
    float w0 = s2 * s * k6;
    float w3 = t2 * t * k6;
    float w1 = fmaf(t2, fmaf(t, 0.5f, -1.0f), 2.0f / 3.0f);
    float w2 = fmaf(s2, fmaf(s, 0.5f, -1.0f), 2.0f / 3.0f);
    float spline = fmaf(a0, w0, fmaf(a1, w1, fmaf(a2, w2, a3 * w3)));
    return fmaf(g_c, xx, spline + s_c);
}

__device__ __forceinline__ void head(float xx, float a_c, float b_c,
                                     float& t, int& ic) {
    float xa = fmaf(xx, a_c, b_c);
    xa = fminf(fmaxf(xa, -1.5f), 1.5f);
    float u  = fmaf(xa, 15.5f, 15.5f);
    float fi = floorf(u);
    t = u - fi;
    int i = (int)fi;
    ic = min(max(i, -2), 33);
}

// ---------- ablation arm: identical chain, NO shfl (arithmetic taps) ----------
__global__ __launch_bounds__(TPB, 1) void kan_spline_ns_kernel(
    const float* __restrict__ x, const float* __restrict__ a,
    const float* __restrict__ b, const float* __restrict__ id_gain,
    const float* __restrict__ bias, float* __restrict__ out)
{
    const int base = blockIdx.x * (TPB * UNROLL) + threadIdx.x;
    const int c = blockIdx.x % NCH;
    float a_c = a[c], b_c = b[c], g_c = id_gain[c], s_c = bias[c];
    const f32x4* __restrict__ x4 = reinterpret_cast<const f32x4*>(x);
    f32x4* __restrict__ o4 = reinterpret_cast<f32x4*>(out);
    #pragma unroll 1
    for (int p = 0; p < 3; ++p) {
        #pragma unroll
        for (int k = 0; k < UNROLL; ++k) {
            f32x4 v = x4[base + k * TPB];
            f32x4 ov;
            #pragma unroll
            for (int e = 0; e < 4; ++e) {
                float t; int ic;
                head(v[e], a_c, b_c, t, ic);
                // taps WITHOUT ds_bpermute: cheap junk arithmetic on ic
                unsigned plo = (unsigned)ic * 0x01010101u + 0x3f803f80u;
                unsigned phi = plo ^ 0x00010001u;
                ov[e] = spline_tail(v[e], t, g_c, s_c, plo, phi);
            }
            o4[base + k * TPB] = ov;
        }
        asm volatile("" ::: "memory");           // force real re-loads next pass
        __builtin_amdgcn_s_waitcnt(0);
        __builtin_amdgcn_sched_barrier(0);
    }
}

// ---------- real kernel (R8 math, high-VGPR, no sched_barrier) ----------
__global__ __launch_bounds__(TPB, 1) void kan_cubic_kernel(
    const float* __restrict__ x, const float* __restrict__ a,
    const float* __restrict__ b, const float* __restrict__ alpha,
    const float* __restrict__ id_gain, const float* __restrict__ bias,
    float* __restrict__ out)
{
    const int tid  = threadIdx.x;
    const int lane = tid & 63;
    const int blk  = blockIdx.x;
    const int base = blk * (TPB * UNROLL) + tid;

    const int c = blk % NCH;
    float a_c = a[c], b_c = b[c], g_c = id_gain[c], s_c = bias[c];
    // pair table in lane regs: lane L -> (ext[L-3], ext[L-2]) as bf16x2
    int kl = min(max(lane - 3, 0), 31);
    int kh = min(max(lane - 2, 0), 31);
    unsigned pk = (bf16_rtn(alpha[(c << 5) + kh]) << 16) | bf16_rtn(alpha[(c << 5) + kl]);

    const f32x4* __restrict__ x4 = reinterpret_cast<const f32x4*>(x);
    f32x4* __restrict__ o4 = reinterpret_cast<f32x4*>(out);

    #pragma unroll
    for (int k = 0; k < UNROLL; ++k) {
        f32x4 v = x4[base + k * TPB];
        f32x4 ov;
        #pragma unroll
        for (int e = 0; e < 4; ++e) {
            float t; int ic;
            head(v[e], a_c, b_c, t, ic);
            unsigned plo = __shfl(pk, ic + 2, 64);  // (ext[ic-1], ext[ic])
            unsigned phi = __shfl(pk, ic + 4, 64);  // (ext[ic+1], ext[ic+2])
            ov[e] = spline_tail(v[e], t, g_c, s_c, plo, phi);
        }
        o4[base + k * TPB] = ov;
    }
}

extern "C" void kernel_launch(void* const* d_in, const int* in_sizes, int n_in,
                              void* d_out, int out_size, void* d_ws, size_t ws_size,
                              hipStream_t stream) {
    const float* x       = (const float*)d_in[0];
    const float* a       = (const float*)d_in[1];
    const float* b       = (const float*)d_in[2];
    const float* alpha   = (const float*)d_in[3];
    const float* id_gain = (const float*)d_in[4];
    const float* bias    = (const float*)d_in[5];
    float* out = (float*)d_out;
    // ablation arm first (x3 passes inside one dispatch), real kernel LAST
    kan_spline_ns_kernel<<<BLOCKS, TPB, 0, stream>>>(x, a, b, id_gain, bias, out);
    kan_cubic_kernel<<<BLOCKS, TPB, 0, stream>>>(x, a, b, alpha, id_gain, bias, out);
}

// Round 11
// 183.892 us; speedup vs baseline: 1.3119x; 1.1456x over previous
//
#include <hip/hip_runtime.h>

// KAN cubic-spline elementwise: out = id_gain[c]*x + spline(clamp(a[c]*x+b[c])) + bias[c]
// B=32,C=192,H=64,W=64,K=32. fp32. HBM traffic ~147MB (L3 absorbs half the fetch)
// -> floor ~23us.
// HISTORY: R2-R8 all ~59-67us with every pipe <35%. Root cause (R10 ablation):
// single-arg __launch_bounds__(256) made the compiler target max occupancy ->
// <=32 VGPR -> fully serialized per-element chains, no cross-element ILP; my
// sched_barrier(0) "prefetch pins" made it worse. Fix: __launch_bounds__(256,1)
// (VGPR-unconstrained), NO sched_barrier -> compiler software-pipelines 16
// elements -> ~26us (decoded from R10 totals).
// Structure: block owns one contiguous plane (1024 f32x4); channel block-uniform
// -> scalar param loads; alpha row as bf16-pair table in lane regs (2 shfl/elem;
// bf16 taps OK: absmax 0.0625 << 0.395 threshold).

#define NCH     192
#define TPB     256
#define UNROLL  4
#define BLOCKS  6144                 // 6144 * 256 * 4 = 6,291,456 f32x4 exactly

typedef float f32x4 __attribute__((ext_vector_type(4)));

__device__ __forceinline__ unsigned bf16_rtn(float f) {
    unsigned u = __builtin_bit_cast(unsigned, f);
    return (u + 0x7FFFu + ((u >> 16) & 1u)) >> 16;   // round-to-nearest-even bf16
}
__device__ __forceinline__ float lo_bf16(unsigned p) {
    unsigned v = p << 16;  return __builtin_bit_cast(float, v);
}
__device__ __forceinline__ float hi_bf16(unsigned p) {
    unsigned v = p & 0xFFFF0000u;  return __builtin_bit_cast(float, v);
}

__device__ __forceinline__ float kan_elem(float xx, float a_c, float b_c,
                                          float g_c, float s_c, unsigned pk) {
    float xa = fmaf(xx, a_c, b_c);
    xa = fminf(fmaxf(xa, -1.5f), 1.5f);
    float u  = fmaf(xa, 15.5f, 15.5f);   // (xa+1) * 0.5*(K-1); u in [-7.75, 38.75]
    float fi = floorf(u);
    float t  = u - fi;                   // weights use UNclamped i (ref semantics)
    int   i  = (int)fi;
    int   ic = min(max(i, -2), 33);      // taps saturate identically beyond this
    // pair table: lane ic+2 holds (ext[ic-1],ext[ic]); lane ic+4 holds (ext[ic+1],ext[ic+2])
    unsigned plo = __shfl(pk, ic + 2, 64);
    unsigned phi = __shfl(pk, ic + 4, 64);
    float a0 = lo_bf16(plo), a1 = hi_bf16(plo);
    float a2 = lo_bf16(phi), a3 = hi_bf16(phi);
    float s  = 1.0f - t;
    float t2 = t * t, s2 = s * s;
    const float k6 = 1.0f / 6.0f;
    float w0 = s2 * s * k6;              // (1-t)^3/6
    float w3 = t2 * t * k6;              // t^3/6
    float w1 = fmaf(t2, fmaf(t, 0.5f, -1.0f), 2.0f / 3.0f);  // (4-6t^2+3t^3)/6
    float w2 = fmaf(s2, fmaf(s, 0.5f, -1.0f), 2.0f / 3.0f);  // symmetric in s
    float spline = fmaf(a0, w0, fmaf(a1, w1, fmaf(a2, w2, a3 * w3)));
    return fmaf(g_c, xx, spline + s_c);
}

__global__ __launch_bounds__(TPB, 1) void kan_cubic_kernel(
    const float* __restrict__ x, const float* __restrict__ a,
    const float* __restrict__ b, const float* __restrict__ alpha,
    const float* __restrict__ id_gain, const float* __restrict__ bias,
    float* __restrict__ out)
{
    const int tid  = threadIdx.x;
    const int lane = tid & 63;
    const int blk  = blockIdx.x;
    const int base = blk * (TPB * UNROLL) + tid;   // block owns one contiguous plane

    const int c = blk % NCH;                       // block-uniform -> scalar loads
    float a_c = a[c], b_c = b[c], g_c = id_gain[c], s_c = bias[c];
    // pair table in lane regs: lane L -> (ext[L-3], ext[L-2]) as bf16x2,
    // ext[k] = alpha[c][clamp(k,0,31)]
    int kl = min(max(lane - 3, 0), 31);
    int kh = min(max(lane - 2, 0), 31);
    unsigned pk = (bf16_rtn(alpha[(c << 5) + kh]) << 16) | bf16_rtn(alpha[(c << 5) + kl]);

    const f32x4* __restrict__ x4 = reinterpret_cast<const f32x4*>(x);
    f32x4* __restrict__ o4 = reinterpret_cast<f32x4*>(out);

    #pragma unroll
    for (int k = 0; k < UNROLL; ++k) {
        f32x4 v = x4[base + k * TPB];
        f32x4 ov;
        #pragma unroll
        for (int e = 0; e < 4; ++e)
            ov[e] = kan_elem(v[e], a_c, b_c, g_c, s_c, pk);
        o4[base + k * TPB] = ov;
    }
}

extern "C" void kernel_launch(void* const* d_in, const int* in_sizes, int n_in,
                              void* d_out, int out_size, void* d_ws, size_t ws_size,
                              hipStream_t stream) {
    const float* x       = (const float*)d_in[0];
    const float* a       = (const float*)d_in[1];
    const float* b       = (const float*)d_in[2];
    const float* alpha   = (const float*)d_in[3];
    const float* id_gain = (const float*)d_in[4];
    const float* bias    = (const float*)d_in[5];
    float* out = (float*)d_out;
    kan_cubic_kernel<<<BLOCKS, TPB, 0, stream>>>(x, a, b, alpha, id_gain, bias, out);
}